// Round 3
// baseline (1068.818 us; speedup 1.0000x reference)
//
#include <hip/hip_runtime.h>

#define N_NODES 100000
#define N_PAD   100352        // 392*256
#define N_EDGES 3200000
#define IN_DIM  128
#define HID     64
#define N_GRAPHS 256
#define CAP     64            // slab capacity per node; deg ~ Poisson(32)
#define OVF_CAP 4096
#define SCAT_BLOCKS  (N_EDGES / 256)   // 12500
#define GEMM1_BLOCKS (N_NODES / 4)     // 25000

// ---------- init: cursor = 0, ocur = 0 ----------
__global__ __launch_bounds__(256) void init_kernel(int* cursor, int* ocur) {
    int i = blockIdx.x * 256 + threadIdx.x;   // grid 392 covers N_PAD exactly
    cursor[i] = 0;
    if (i == 0) ocur[0] = 0;
}

// ---------- fused: slab scatter (blocks 0..12499) + gemm1 (blocks 12500..37499) ----------
// scatter: slab[col*CAP + pos] = edge_id  (pos from cursor atomic; rare overflow -> ovf list)
// gemm1:   xl = x @ W1
__global__ __launch_bounds__(256) void scatter_gemm1_kernel(
        const int* __restrict__ row, const int* __restrict__ col,
        int* cursor, int* ocur, int* __restrict__ ovf_e, int* __restrict__ ovf_c,
        int* __restrict__ slab,
        const float* __restrict__ x, const float* __restrict__ W1,
        float* __restrict__ xl) {
    __shared__ float sW[IN_DIM * HID];   // 32 KB
    __shared__ float sx[4][IN_DIM];      // 2 KB
    if (blockIdx.x < SCAT_BLOCKS) {
        int e = blockIdx.x * 256 + threadIdx.x;
        int c = col[e];
        int pos = atomicAdd(&cursor[c], 1);
        if (pos < CAP) {
            slab[c * CAP + pos] = e;
        } else {
            int op = atomicAdd(ocur, 1);
            if (op < OVF_CAP) { ovf_e[op] = e; ovf_c[op] = c; }
        }
    } else {
        int bid = blockIdx.x - SCAT_BLOCKS;
        int tid = threadIdx.x;
        const float4* W4  = (const float4*)W1;
        float4*       sW4 = (float4*)sW;
        #pragma unroll
        for (int i = 0; i < 8; ++i) sW4[tid + 256 * i] = W4[tid + 256 * i];
        int r0 = bid * 4;
        const float4* x4  = (const float4*)(x + (size_t)r0 * IN_DIM);
        float4*       sx4 = (float4*)&sx[0][0];
        if (tid < 128) sx4[tid] = x4[tid];
        __syncthreads();
        int lr = tid >> 6, c = tid & 63;
        float acc = 0.f;
        #pragma unroll 8
        for (int k = 0; k < IN_DIM; ++k) acc += sx[lr][k] * sW[k * HID + c];
        xl[(size_t)(r0 + lr) * HID + c] = acc;
    }
}

// ---------- deg/dis from slab: dis[n] = 1/sqrt(1 + sum ew over in-edges) ----------
__global__ __launch_bounds__(256) void deg_dis_kernel(const int* __restrict__ slab,
                                                      const int* __restrict__ cursor,
                                                      const float* __restrict__ ew,
                                                      const int* __restrict__ ovf_e,
                                                      const int* __restrict__ ovf_c,
                                                      const int* __restrict__ ocur,
                                                      float* __restrict__ dis) {
    int t = blockIdx.x * 256 + threadIdx.x;   // grid 6250: 16 lanes per node
    int n = t >> 4, l = t & 15;
    int cur  = cursor[n];
    int kept = cur < CAP ? cur : CAP;
    float s = 0.f;
    for (int j = l; j < kept; j += 16) s += ew[slab[n * CAP + j]];
    s += __shfl_down(s, 8, 16);
    s += __shfl_down(s, 4, 16);
    s += __shfl_down(s, 2, 16);
    s += __shfl_down(s, 1, 16);
    if (l == 0) {
        if (cur > CAP) {
            int oc = min(*ocur, OVF_CAP);
            for (int j = 0; j < oc; ++j)
                if (ovf_c[j] == n) s += ew[ovf_e[j]];
        }
        float d = 1.0f + s;   // self-loop weight 1; always > 0
        dis[n] = 1.0f / sqrtf(fmaxf(d, 1e-30f));
    }
}

// ---------- gather: agg[n] = xl[n]*dis[n]^2 + sum_j dis[r]*ew*dis[n] * xl[r] ----------
// wave per node; quarter q handles slab entries q, q+4, ...; 16 lanes x float4 channels
__global__ __launch_bounds__(256) void gather_kernel(const int* __restrict__ slab,
                                                     const int* __restrict__ cursor,
                                                     const int* __restrict__ row,
                                                     const float* __restrict__ ew,
                                                     const float* __restrict__ dis,
                                                     const int* __restrict__ ovf_e,
                                                     const int* __restrict__ ovf_c,
                                                     const int* __restrict__ ocur,
                                                     const float* __restrict__ xl,
                                                     float* __restrict__ agg) {
    int n    = (blockIdx.x * 256 + threadIdx.x) >> 6;   // grid 25000 exact
    int lane = threadIdx.x & 63;
    int q    = lane >> 4;
    int c0   = (lane & 15) << 2;
    int cur  = cursor[n];
    int kept = cur < CAP ? cur : CAP;
    float disc = dis[n];
    float4 acc = make_float4(0.f, 0.f, 0.f, 0.f);
    if (q == 0) {
        float d2 = disc * disc;
        float4 xs = *(const float4*)(xl + (size_t)n * HID + c0);
        acc = make_float4(xs.x * d2, xs.y * d2, xs.z * d2, xs.w * d2);
    }
    for (int j = q; j < kept; j += 4) {
        int   e = slab[n * CAP + j];
        int   r = row[e];
        float w = dis[r] * ew[e] * disc;
        float4 xv = *(const float4*)(xl + (size_t)r * HID + c0);
        acc.x += xv.x * w; acc.y += xv.y * w;
        acc.z += xv.z * w; acc.w += xv.w * w;
    }
    if (q == 0 && cur > CAP) {          // essentially never taken
        int oc = min(*ocur, OVF_CAP);
        for (int j = 0; j < oc; ++j) {
            if (ovf_c[j] == n) {
                int   e = ovf_e[j];
                int   r = row[e];
                float w = dis[r] * ew[e] * disc;
                float4 xv = *(const float4*)(xl + (size_t)r * HID + c0);
                acc.x += xv.x * w; acc.y += xv.y * w;
                acc.z += xv.z * w; acc.w += xv.w * w;
            }
        }
    }
    acc.x += __shfl_down(acc.x, 32, 64); acc.y += __shfl_down(acc.y, 32, 64);
    acc.z += __shfl_down(acc.z, 32, 64); acc.w += __shfl_down(acc.w, 32, 64);
    acc.x += __shfl_down(acc.x, 16, 64); acc.y += __shfl_down(acc.y, 16, 64);
    acc.z += __shfl_down(acc.z, 16, 64); acc.w += __shfl_down(acc.w, 16, 64);
    if (lane < 16) *(float4*)(agg + (size_t)n * HID + c0) = acc;
}

// ---------- layer 2 GEMM: xl2 = relu(agg1 + b1) @ W2 ----------
__global__ __launch_bounds__(256) void gemm2_kernel(const float* __restrict__ agg1,
                                                    const float* __restrict__ W2,
                                                    const float* __restrict__ b1,
                                                    float* __restrict__ xl2) {
    __shared__ float sW[HID * HID];      // 16 KB
    __shared__ float sh[4][HID];
    int tid = threadIdx.x;
    const float4* W4  = (const float4*)W2;
    float4*       sW4 = (float4*)sW;
    #pragma unroll
    for (int i = 0; i < 4; ++i) sW4[tid + 256 * i] = W4[tid + 256 * i];
    int r0 = blockIdx.x * 4;
    int lr = tid >> 6, c = tid & 63;
    float v = agg1[(size_t)(r0 + lr) * HID + c] + b1[c];
    sh[lr][c] = v > 0.f ? v : 0.f;
    __syncthreads();
    float acc = 0.f;
    #pragma unroll 8
    for (int k = 0; k < HID; ++k) acc += sh[lr][k] * sW[k * HID + c];
    xl2[(size_t)(r0 + lr) * HID + c] = acc;
}

// ---------- pooling + head: out[g] = mean_i relu(agg2[i]+b2) . Wc + bc ----------
__global__ __launch_bounds__(256) void pool_head_kernel(const float* __restrict__ agg2,
                                                        const float* __restrict__ b2,
                                                        const int* __restrict__ batch,
                                                        const float* __restrict__ Wc,
                                                        const float* __restrict__ bc,
                                                        float* __restrict__ out) {
    int g = blockIdx.x;
    int lo = 0, hi = N_NODES;
    while (lo < hi) { int m = (lo + hi) >> 1; if (batch[m] < g) lo = m + 1; else hi = m; }
    int start = lo;
    hi = N_NODES;
    while (lo < hi) { int m = (lo + hi) >> 1; if (batch[m] < g + 1) lo = m + 1; else hi = m; }
    int end = lo;
    int w = threadIdx.x >> 6, lane = threadIdx.x & 63;
    float bb = b2[lane];
    float acc = 0.f;
    for (int i = start + w; i < end; i += 4) {
        float v = agg2[(size_t)i * HID + lane] + bb;
        acc += v > 0.f ? v : 0.f;
    }
    __shared__ float s[4][HID];
    s[w][lane] = acc;
    __syncthreads();
    if (w == 0) {
        float p = s[0][lane] + s[1][lane] + s[2][lane] + s[3][lane];
        float cntf = (float)(end - start);
        p = p / fmaxf(cntf, 1.0f) * Wc[lane];
        #pragma unroll
        for (int o = 32; o > 0; o >>= 1) p += __shfl_down(p, o, 64);
        if (lane == 0) out[g] = p + bc[0];
    }
}

extern "C" void kernel_launch(void* const* d_in, const int* in_sizes, int n_in,
                              void* d_out, int out_size, void* d_ws, size_t ws_size,
                              hipStream_t stream) {
    const float* x     = (const float*)d_in[0];
    const int*   ei    = (const int*)  d_in[1];
    const float* ew    = (const float*)d_in[2];
    const int*   batch = (const int*)  d_in[3];
    const float* W1    = (const float*)d_in[4];
    const float* b1    = (const float*)d_in[5];
    const float* W2    = (const float*)d_in[6];
    const float* b2    = (const float*)d_in[7];
    const float* Wc    = (const float*)d_in[8];
    const float* bc    = (const float*)d_in[9];
    float* out = (float*)d_out;

    const int* row = ei;             // ei[0,:]
    const int* col = ei + N_EDGES;   // ei[1,:]

    // workspace layout (4-byte units), total ~77.6 MB
    int*   cursor = (int*)d_ws;                    // N_PAD
    int*   ocur   = cursor + N_PAD;                // 256 (pad)
    int*   ovf_e  = ocur + 256;                    // OVF_CAP
    int*   ovf_c  = ovf_e + OVF_CAP;               // OVF_CAP
    int*   slab   = ovf_c + OVF_CAP;               // N_NODES*CAP
    float* dis    = (float*)(slab + (size_t)N_NODES * CAP);   // N_PAD
    float* bufA   = dis + N_PAD;                   // N*HID (16B-aligned offset)
    float* bufB   = bufA + (size_t)N_NODES * HID;  // N*HID

    init_kernel<<<N_PAD / 256, 256, 0, stream>>>(cursor, ocur);
    scatter_gemm1_kernel<<<SCAT_BLOCKS + GEMM1_BLOCKS, 256, 0, stream>>>(
        row, col, cursor, ocur, ovf_e, ovf_c, slab, x, W1, bufA);
    deg_dis_kernel<<<(N_NODES * 16) / 256, 256, 0, stream>>>(
        slab, cursor, ew, ovf_e, ovf_c, ocur, dis);
    gather_kernel<<<N_NODES / 4, 256, 0, stream>>>(
        slab, cursor, row, ew, dis, ovf_e, ovf_c, ocur, bufA, bufB);
    gemm2_kernel<<<N_NODES / 4, 256, 0, stream>>>(bufB, W2, b1, bufA);
    gather_kernel<<<N_NODES / 4, 256, 0, stream>>>(
        slab, cursor, row, ew, dis, ovf_e, ovf_c, ocur, bufA, bufB);
    pool_head_kernel<<<N_GRAPHS, 256, 0, stream>>>(bufB, b2, batch, Wc, bc, out);
}